// Round 7
// baseline (196.902 us; speedup 1.0000x reference)
//
#include <hip/hip_runtime.h>
#include <math.h>

constexpr int B_  = 2;
constexpr int N_  = 10000;
constexpr int E_  = 160000;
constexpr int H_  = 128;
constexpr int ET_ = 8;
constexpr float EPS_ = 1e-5f;
constexpr float RSQH = 0.08838834764831845f; // 1/sqrt(128)

typedef __bf16 bf16x8 __attribute__((ext_vector_type(8)));
typedef short  short8 __attribute__((ext_vector_type(8)));
typedef float  f32x4  __attribute__((ext_vector_type(4)));
typedef unsigned short u16;

__device__ inline u16 bf16b(float f) {
    return __builtin_bit_cast(u16, (__bf16)f);
}

__device__ inline bf16x8 ldfrag(const u16* __restrict__ W, int kc, int nt, int lane) {
    short8 s = *(const short8*)(W + ((kc * 8 + nt) * 64 + lane) * 8);
    return __builtin_bit_cast(bf16x8, s);
}

// ---------------------------------------------------------------------------
// Fused setup: blocks [0,56) weight-prep, [56,64) edge-type tables,
// [64,689) tgt histogram.
// ---------------------------------------------------------------------------
__global__ __launch_bounds__(256)
void setup_kernel(const float* __restrict__ W1, const float* __restrict__ W2,
                  const float* __restrict__ Wq, const float* __restrict__ Wk,
                  const float* __restrict__ Wv,
                  u16* __restrict__ W1s, u16* __restrict__ W2s,
                  u16* __restrict__ Wqs, u16* __restrict__ Wks, u16* __restrict__ Wvs,
                  const float* __restrict__ edge_emb,
                  const float* __restrict__ bk, const float* __restrict__ bv,
                  const float* __restrict__ We, const float* __restrict__ be,
                  float* __restrict__ Kt, float* __restrict__ Vt, float* __restrict__ eb,
                  const int* __restrict__ tgt, int* __restrict__ hist)
{
    const int bid = blockIdx.x, tid = threadIdx.x;
    if (bid < 56) {
        // weight prep: f32 [Kx128] -> bf16 B-frag swizzle
        int unit = bid >> 1, half = bid & 1;
        const float* src; u16* dst; int kc;
        if (unit < 12)      { src = W1; dst = W1s; kc = unit; }
        else if (unit < 16) { src = W2; dst = W2s; kc = unit - 12; }
        else if (unit < 20) { src = Wq; dst = Wqs; kc = unit - 16; }
        else if (unit < 24) { src = Wk; dst = Wks; kc = unit - 20; }
        else                { src = Wv; dst = Wvs; kc = unit - 24; }
        int nt = half * 4 + (tid >> 6), lane = tid & 63;
        int q = lane >> 4, c = lane & 15;
        int kbase = kc * 32 + q * 8;
        int col = nt * 16 + c;
        u16* out = dst + ((kc * 8 + nt) * 64 + lane) * 8;
#pragma unroll
        for (int j = 0; j < 8; ++j)
            out[j] = bf16b(src[(kbase + j) * H_ + col]);
    } else if (bid < 64) {
        // edge-type tables: Kt=e@Wk+bk, Vt=e@Wv+bv, eb=e@We+be
        int t = bid - 56;
        const float* ep = edge_emb + t * H_;
        __shared__ float red[2];
        int j = tid;
        if (j < 128) {
            float ak = bk[j], av = bv[j];
            for (int d = 0; d < H_; d += 4) {
                float e0 = ep[d], e1 = ep[d+1], e2 = ep[d+2], e3 = ep[d+3];
                ak += e0*Wk[(d+0)*H_+j] + e1*Wk[(d+1)*H_+j] + e2*Wk[(d+2)*H_+j] + e3*Wk[(d+3)*H_+j];
                av += e0*Wv[(d+0)*H_+j] + e1*Wv[(d+1)*H_+j] + e2*Wv[(d+2)*H_+j] + e3*Wv[(d+3)*H_+j];
            }
            Kt[t*H_ + j] = ak;
            Vt[t*H_ + j] = av;
            float pe = ep[j] * We[j];
#pragma unroll
            for (int off = 32; off; off >>= 1) pe += __shfl_xor(pe, off);
            if ((j & 63) == 0) red[j >> 6] = pe;
        }
        __syncthreads();
        if (j == 0) eb[t] = red[0] + red[1] + be[0];
    } else {
        int e = (bid - 64) * 256 + tid;
        if (e < E_) atomicAdd(&hist[tgt[e]], 1);
    }
}

// ---------------------------------------------------------------------------
// Single-pass exclusive scan: 1024 threads x 10 elements, 2 barriers.
// ---------------------------------------------------------------------------
__global__ __launch_bounds__(1024)
void scan_kernel(const int* __restrict__ hist, int* __restrict__ offs,
                 int* __restrict__ cursor)
{
    __shared__ int winc[16];
    const int tid = threadIdx.x, wave = tid >> 6, lane = tid & 63;
    int v[10];
    const int idx0 = tid * 10;
    int tot = 0;
#pragma unroll
    for (int i = 0; i < 10; ++i) {
        int idx = idx0 + i;
        v[i] = (idx < N_) ? hist[idx] : 0;
        tot += v[i];
    }
    int s = tot;
#pragma unroll
    for (int off = 1; off < 64; off <<= 1) {
        int t = __shfl_up(s, off);
        if (lane >= off) s += t;
    }
    if (lane == 63) winc[wave] = s;
    __syncthreads();
    if (tid < 16) {
        int si = winc[tid];
#pragma unroll
        for (int off = 1; off < 16; off <<= 1) {
            int t = __shfl_up(si, off);
            if (tid >= off) si += t;
        }
        winc[tid] = si;   // inclusive scan of wave totals
    }
    __syncthreads();
    int wbase = (wave == 0) ? 0 : winc[wave - 1];
    int run = wbase + (s - tot);
#pragma unroll
    for (int i = 0; i < 10; ++i) {
        int idx = idx0 + i;
        if (idx < N_) { offs[idx] = run; cursor[idx] = run; }
        run += v[i];
    }
    if (tid == 0) offs[N_] = winc[15];
}

// ---------------------------------------------------------------------------
// Fused scatter (blocks [0,625)) + Q/K/V MFMA (blocks [625,938)).
// qkv epilogue also emits biasT[bn][t] = (Q . Kt[t]) * RSQH + eb[t]
// from the in-register f32 accumulators (removes per-wave bias work in attn).
// ---------------------------------------------------------------------------
__global__ __launch_bounds__(256)
void scatter_qkv_kernel(const int* __restrict__ src, const int* __restrict__ tgt,
                        const int* __restrict__ type, int* __restrict__ cursor,
                        int* __restrict__ sorted,
                        const float* __restrict__ hidden, const float* __restrict__ time_emb,
                        const u16* __restrict__ Wqs, const u16* __restrict__ Wks,
                        const u16* __restrict__ Wvs, const float* __restrict__ bq,
                        const float* __restrict__ KtF, const float* __restrict__ ebt,
                        u16* __restrict__ Q, u16* __restrict__ K, u16* __restrict__ V,
                        float* __restrict__ biasT)
{
    if (blockIdx.x < 625) {
        int e = blockIdx.x * 256 + threadIdx.x;
        if (e < E_) {
            int t = tgt[e];
            int pos = atomicAdd(&cursor[t], 1);
            sorted[pos] = src[e] | (type[e] << 16);
        }
        return;
    }
    const int wv = threadIdx.x >> 6, lane = threadIdx.x & 63;
    const int tile = (blockIdx.x - 625) * 4 + wv;
    if (tile >= (B_ * N_) / 16) return;
    const int nbase = tile * 16;
    const int m = lane & 15, q = lane >> 4;
    const int koff = q * 8;

    bf16x8 aq[4], av[4];
    const float* hp = hidden   + (nbase + m) * H_ + koff;
    const float* tp = time_emb + (nbase + m) * H_ + koff;
#pragma unroll
    for (int kc = 0; kc < 4; ++kc) {
        float4 h0 = *(const float4*)(hp + kc * 32);
        float4 h1 = *(const float4*)(hp + kc * 32 + 4);
        float4 t0 = *(const float4*)(tp + kc * 32);
        float4 t1 = *(const float4*)(tp + kc * 32 + 4);
        bf16x8 fv, fq;
        fv[0]=(__bf16)h0.x; fv[1]=(__bf16)h0.y; fv[2]=(__bf16)h0.z; fv[3]=(__bf16)h0.w;
        fv[4]=(__bf16)h1.x; fv[5]=(__bf16)h1.y; fv[6]=(__bf16)h1.z; fv[7]=(__bf16)h1.w;
        fq[0]=(__bf16)(h0.x+t0.x); fq[1]=(__bf16)(h0.y+t0.y);
        fq[2]=(__bf16)(h0.z+t0.z); fq[3]=(__bf16)(h0.w+t0.w);
        fq[4]=(__bf16)(h1.x+t1.x); fq[5]=(__bf16)(h1.y+t1.y);
        fq[6]=(__bf16)(h1.z+t1.z); fq[7]=(__bf16)(h1.w+t1.w);
        av[kc] = fv; aq[kc] = fq;
    }

    f32x4 accq[8], acck[8], accv[8];
#pragma unroll
    for (int nt = 0; nt < 8; ++nt) { accq[nt] = (f32x4)0.f; acck[nt] = (f32x4)0.f; accv[nt] = (f32x4)0.f; }

#pragma unroll
    for (int kc = 0; kc < 4; ++kc) {
#pragma unroll
        for (int nt = 0; nt < 8; ++nt) {
            bf16x8 bfq = ldfrag(Wqs, kc, nt, lane);
            bf16x8 bfk = ldfrag(Wks, kc, nt, lane);
            bf16x8 bfv = ldfrag(Wvs, kc, nt, lane);
            accq[nt] = __builtin_amdgcn_mfma_f32_16x16x32_bf16(aq[kc], bfq, accq[nt], 0, 0, 0);
            acck[nt] = __builtin_amdgcn_mfma_f32_16x16x32_bf16(aq[kc], bfk, acck[nt], 0, 0, 0);
            accv[nt] = __builtin_amdgcn_mfma_f32_16x16x32_bf16(av[kc], bfv, accv[nt], 0, 0, 0);
        }
    }

    float bqv[8];
#pragma unroll
    for (int nt = 0; nt < 8; ++nt) bqv[nt] = bq[nt * 16 + m];

    // bias table: biasT[node][t] = sum_col Q[node][col]*Kt[t][col]*RSQH + eb[t]
#pragma unroll
    for (int t = 0; t < ET_; ++t) {
        float kt[8];
#pragma unroll
        for (int nt = 0; nt < 8; ++nt) kt[nt] = KtF[t * H_ + nt * 16 + m];
        float ebv = ebt[t];
#pragma unroll
        for (int r = 0; r < 4; ++r) {
            float s = 0.f;
#pragma unroll
            for (int nt = 0; nt < 8; ++nt) s += (accq[nt][r] + bqv[nt]) * kt[nt];
#pragma unroll
            for (int msk = 1; msk < 16; msk <<= 1) s += __shfl_xor(s, msk);
            if (m == 0)
                biasT[(nbase + q * 4 + r) * ET_ + t] = s * RSQH + ebv;
        }
    }

#pragma unroll
    for (int nt = 0; nt < 8; ++nt) {
        int col = nt * 16 + m;
#pragma unroll
        for (int r = 0; r < 4; ++r) {
            int node = nbase + q * 4 + r;
            Q[node * H_ + col] = bf16b(accq[nt][r] + bqv[nt]);
            K[node * H_ + col] = bf16b(acck[nt][r]);
            V[node * H_ + col] = bf16b(accv[nt][r]);
        }
    }
}

// ---------------------------------------------------------------------------
// Attention: one wave per (b,node); 16-lane groups own edges, 2 in flight.
// SINGLE pass: per-group online softmax (m,l,acc), K+V gathers issued in the
// same iteration; groups merged once at the end with exact max-rescaling.
// Per-type bias from precomputed biasT (32B/wave).
// ---------------------------------------------------------------------------
__global__ __launch_bounds__(256)
void attn_kernel(const u16* __restrict__ Qb, const u16* __restrict__ Kb,
                 const u16* __restrict__ Vb, const float* __restrict__ Vt,
                 const float* __restrict__ biasT,
                 const int* __restrict__ offs, const int* __restrict__ sorted,
                 u16* __restrict__ aggb)
{
    __shared__ float bias_s[4][8];
    __shared__ int   pk_s[4][64];
    __shared__ __align__(16) u16 vt_s[8][128];

    const int tid = threadIdx.x;
    const int wv = tid >> 6, lane = tid & 63;
    const int g = lane >> 4, lam = lane & 63 & 15;

    for (int idx = tid; idx < ET_ * H_; idx += 256)
        vt_s[idx >> 7][idx & 127] = bf16b(Vt[idx]);
    __syncthreads();

    const int b = blockIdx.x & 1;                 // batch-parity XCD swizzle
    const int n = (blockIdx.x >> 1) * 4 + wv;
    const int bn = b * N_ + n;
    const int beg = offs[n], end = offs[n + 1];
    const int bbase = b * N_;

    if (lane < 8) bias_s[wv][lane] = biasT[bn * ET_ + lane];

    float q[8];
    {
        short8 s8 = *(const short8*)(Qb + (size_t)bn * H_ + lam * 8);
        bf16x8 qa = __builtin_bit_cast(bf16x8, s8);
#pragma unroll
        for (int j = 0; j < 8; ++j) q[j] = (float)qa[j];
    }

    float m_g = -INFINITY, l_g = 0.f;
    float acc[8];
#pragma unroll
    for (int j = 0; j < 8; ++j) acc[j] = 0.f;

    for (int cb = beg; cb < end; cb += 64) {
        const int cnt = min(64, end - cb);
        pk_s[wv][lane] = (cb + lane < end) ? sorted[cb + lane] : 0;  // pre-divergence

        int c = g;
        for (; c + 4 < cnt; c += 8) {
            int pk0 = pk_s[wv][c];
            int pk1 = pk_s[wv][c + 4];
            int s0 = pk0 & 0xFFFF, t0 = pk0 >> 16;
            int s1 = pk1 & 0xFFFF, t1 = pk1 >> 16;
            short8 k80 = *(const short8*)(Kb + (size_t)(bbase + s0) * H_ + lam * 8);
            short8 k81 = *(const short8*)(Kb + (size_t)(bbase + s1) * H_ + lam * 8);
            short8 v80 = *(const short8*)(Vb + (size_t)(bbase + s0) * H_ + lam * 8);
            short8 v81 = *(const short8*)(Vb + (size_t)(bbase + s1) * H_ + lam * 8);
            short8 vt80 = *(const short8*)(&vt_s[t0][lam * 8]);
            short8 vt81 = *(const short8*)(&vt_s[t1][lam * 8]);
            bf16x8 ka0 = __builtin_bit_cast(bf16x8, k80);
            bf16x8 ka1 = __builtin_bit_cast(bf16x8, k81);
            float p0 = 0.f, p1 = 0.f;
#pragma unroll
            for (int j = 0; j < 8; ++j) {
                p0 += q[j] * (float)ka0[j];
                p1 += q[j] * (float)ka1[j];
            }
#pragma unroll
            for (int msk = 1; msk < 16; msk <<= 1) {
                p0 += __shfl_xor(p0, msk);
                p1 += __shfl_xor(p1, msk);
            }
            float lg0 = p0 * RSQH + bias_s[wv][t0];
            float lg1 = p1 * RSQH + bias_s[wv][t1];
            float nm = fmaxf(m_g, fmaxf(lg0, lg1));
            float sc = __expf(m_g - nm);          // first iter: exp(-inf)=0
            float w0 = __expf(lg0 - nm);
            float w1 = __expf(lg1 - nm);
            l_g = l_g * sc + w0 + w1;
            bf16x8 va0  = __builtin_bit_cast(bf16x8, v80);
            bf16x8 va1  = __builtin_bit_cast(bf16x8, v81);
            bf16x8 vta0 = __builtin_bit_cast(bf16x8, vt80);
            bf16x8 vta1 = __builtin_bit_cast(bf16x8, vt81);
#pragma unroll
            for (int j = 0; j < 8; ++j)
                acc[j] = acc[j] * sc + w0 * ((float)va0[j] + (float)vta0[j])
                                     + w1 * ((float)va1[j] + (float)vta1[j]);
            m_g = nm;
        }
        if (c < cnt) {
            int pk0 = pk_s[wv][c];
            int s0 = pk0 & 0xFFFF, t0 = pk0 >> 16;
            short8 k80 = *(const short8*)(Kb + (size_t)(bbase + s0) * H_ + lam * 8);
            short8 v80 = *(const short8*)(Vb + (size_t)(bbase + s0) * H_ + lam * 8);
            short8 vt80 = *(const short8*)(&vt_s[t0][lam * 8]);
            bf16x8 ka0 = __builtin_bit_cast(bf16x8, k80);
            float p0 = 0.f;
#pragma unroll
            for (int j = 0; j < 8; ++j) p0 += q[j] * (float)ka0[j];
#pragma unroll
            for (int msk = 1; msk < 16; msk <<= 1) p0 += __shfl_xor(p0, msk);
            float lg0 = p0 * RSQH + bias_s[wv][t0];
            float nm = fmaxf(m_g, lg0);
            float sc = __expf(m_g - nm);
            float w0 = __expf(lg0 - nm);
            l_g = l_g * sc + w0;
            bf16x8 va0  = __builtin_bit_cast(bf16x8, v80);
            bf16x8 vta0 = __builtin_bit_cast(bf16x8, vt80);
#pragma unroll
            for (int j = 0; j < 8; ++j)
                acc[j] = acc[j] * sc + w0 * ((float)va0[j] + (float)vta0[j]);
            m_g = nm;
        }
    }

    // merge the 4 groups (all lanes reconverged; m_g/l_g uniform per group)
    float M = fmaxf(m_g, __shfl_xor(m_g, 16));
    M = fmaxf(M, __shfl_xor(M, 32));
    float sc = (l_g > 0.f) ? __expf(m_g - M) : 0.f;   // guard: empty group
    float lw = l_g * sc;
    lw += __shfl_xor(lw, 16);
    lw += __shfl_xor(lw, 32);
#pragma unroll
    for (int j = 0; j < 8; ++j) {
        float a = acc[j] * sc;
        a += __shfl_xor(a, 16);
        a += __shfl_xor(a, 32);
        acc[j] = a;
    }

    if (g == 0) {
        float invL = (end > beg) ? 1.f / lw : 0.f;
        bf16x8 o;
#pragma unroll
        for (int j = 0; j < 8; ++j) o[j] = (__bf16)(acc[j] * invL);
        *(short8*)(aggb + (size_t)bn * H_ + lam * 8) = __builtin_bit_cast(short8, o);
    }
}

// ---------------------------------------------------------------------------
// MLP + residual + LayerNorm via MFMA.
// ---------------------------------------------------------------------------
__global__ __launch_bounds__(256)
void mlp_mfma_kernel(const float* __restrict__ hidden, const u16* __restrict__ aggb,
                     const float* __restrict__ time_emb,
                     const u16* __restrict__ W1s, const u16* __restrict__ W2s,
                     const float* __restrict__ b1, const float* __restrict__ b2,
                     const float* __restrict__ gamma, const float* __restrict__ beta,
                     float* __restrict__ out)
{
    __shared__ __align__(16) u16 h1s[4][16][136];
    const int wv = threadIdx.x >> 6, lane = threadIdx.x & 63;
    const int tile = blockIdx.x * 4 + wv;
    if (tile >= (B_ * N_) / 16) return;
    const int nbase = tile * 16;
    const int m = lane & 15, q = lane >> 4;
    const int koff = q * 8;

    bf16x8 a[12];
    const float* hp = hidden   + (nbase + m) * H_ + koff;
    const float* tp = time_emb + (nbase + m) * H_ + koff;
    const u16*   ap = aggb + (size_t)(nbase + m) * H_ + koff;
#pragma unroll
    for (int kc = 0; kc < 4; ++kc) {
        float4 h0 = *(const float4*)(hp + kc * 32);
        float4 h1 = *(const float4*)(hp + kc * 32 + 4);
        float4 t0 = *(const float4*)(tp + kc * 32);
        float4 t1 = *(const float4*)(tp + kc * 32 + 4);
        bf16x8 fh, ft;
        fh[0]=(__bf16)h0.x; fh[1]=(__bf16)h0.y; fh[2]=(__bf16)h0.z; fh[3]=(__bf16)h0.w;
        fh[4]=(__bf16)h1.x; fh[5]=(__bf16)h1.y; fh[6]=(__bf16)h1.z; fh[7]=(__bf16)h1.w;
        ft[0]=(__bf16)t0.x; ft[1]=(__bf16)t0.y; ft[2]=(__bf16)t0.z; ft[3]=(__bf16)t0.w;
        ft[4]=(__bf16)t1.x; ft[5]=(__bf16)t1.y; ft[6]=(__bf16)t1.z; ft[7]=(__bf16)t1.w;
        a[0 * 4 + kc] = fh;
        a[2 * 4 + kc] = ft;
        short8 s8 = *(const short8*)(ap + kc * 32);
        a[1 * 4 + kc] = __builtin_bit_cast(bf16x8, s8);
    }

    f32x4 acc[8];
#pragma unroll
    for (int nt = 0; nt < 8; ++nt) acc[nt] = (f32x4)0.f;
#pragma unroll
    for (int kc = 0; kc < 12; ++kc) {
#pragma unroll
        for (int nt = 0; nt < 8; ++nt) {
            bf16x8 bf = ldfrag(W1s, kc, nt, lane);
            acc[nt] = __builtin_amdgcn_mfma_f32_16x16x32_bf16(a[kc], bf, acc[nt], 0, 0, 0);
        }
    }

#pragma unroll
    for (int nt = 0; nt < 8; ++nt) {
        int col = nt * 16 + m;
        float bb = b1[col];
#pragma unroll
        for (int r = 0; r < 4; ++r) {
            float v = acc[nt][r] + bb;
            float h = v / (1.f + __expf(-v));
            h1s[wv][q * 4 + r][col] = bf16b(h);
        }
    }

    f32x4 acc2[8];
#pragma unroll
    for (int nt = 0; nt < 8; ++nt) acc2[nt] = (f32x4)0.f;
#pragma unroll
    for (int kc = 0; kc < 4; ++kc) {
        short8 s8 = *(const short8*)&h1s[wv][m][kc * 32 + koff];
        bf16x8 a2 = __builtin_bit_cast(bf16x8, s8);
#pragma unroll
        for (int nt = 0; nt < 8; ++nt) {
            bf16x8 bf = ldfrag(W2s, kc, nt, lane);
            acc2[nt] = __builtin_amdgcn_mfma_f32_16x16x32_bf16(a2, bf, acc2[nt], 0, 0, 0);
        }
    }

    float x[8][4];
#pragma unroll
    for (int nt = 0; nt < 8; ++nt) {
        int col = nt * 16 + m;
        float bb = b2[col];
#pragma unroll
        for (int r = 0; r < 4; ++r) {
            int node = nbase + q * 4 + r;
            x[nt][r] = hidden[node * H_ + col] + acc2[nt][r] + bb;
        }
    }
#pragma unroll
    for (int r = 0; r < 4; ++r) {
        float s = 0.f, ss = 0.f;
#pragma unroll
        for (int nt = 0; nt < 8; ++nt) { s += x[nt][r]; ss += x[nt][r] * x[nt][r]; }
#pragma unroll
        for (int off = 1; off < 16; off <<= 1) {
            s  += __shfl_xor(s, off);
            ss += __shfl_xor(ss, off);
        }
        float mu  = s * (1.f / H_);
        float var = ss * (1.f / H_) - mu * mu;
        float rs  = rsqrtf(var + EPS_);
        int node = nbase + q * 4 + r;
#pragma unroll
        for (int nt = 0; nt < 8; ++nt) {
            int col = nt * 16 + m;
            out[node * H_ + col] = (x[nt][r] - mu) * rs * gamma[col] + beta[col];
        }
    }
}

// ---------------------------------------------------------------------------
extern "C" void kernel_launch(void* const* d_in, const int* in_sizes, int n_in,
                              void* d_out, int out_size, void* d_ws, size_t ws_size,
                              hipStream_t stream)
{
    const float* hidden   = (const float*)d_in[0];
    const float* time_emb = (const float*)d_in[1];
    const int*   eidx     = (const int*)d_in[2];
    const int*   etype    = (const int*)d_in[3];
    const float* edge_emb = (const float*)d_in[4];
    const float* Wq = (const float*)d_in[5];
    const float* bq = (const float*)d_in[6];
    const float* Wk = (const float*)d_in[7];
    const float* bk = (const float*)d_in[8];
    const float* Wv = (const float*)d_in[9];
    const float* bv = (const float*)d_in[10];
    const float* We = (const float*)d_in[11];
    const float* be = (const float*)d_in[12];
    const float* W1 = (const float*)d_in[13];
    const float* b1 = (const float*)d_in[14];
    const float* W2 = (const float*)d_in[15];
    const float* b2 = (const float*)d_in[16];
    const float* gamma = (const float*)d_in[17];
    const float* beta  = (const float*)d_in[18];
    float* out = (float*)d_out;

    constexpr int BNH = B_ * N_ * H_;
    u16* Qb   = (u16*)d_ws;
    u16* Kb   = Qb + BNH;
    u16* Vb   = Kb + BNH;
    u16* aggb = Vb + BNH;
    float* Kt  = (float*)(aggb + BNH);
    float* Vt  = Kt + ET_ * H_;
    float* ebt = Vt + ET_ * H_;
    float* biasT = ebt + ET_;
    int* hist   = (int*)(biasT + B_ * N_ * ET_);
    int* offs   = hist + N_;
    int* cursor = offs + (N_ + 1);
    int* sorted = cursor + N_;
    uintptr_t wp = (uintptr_t)(sorted + E_);
    wp = (wp + 15) & ~(uintptr_t)15;
    u16* W1s = (u16*)wp;
    u16* W2s = W1s + 384 * 128;
    u16* Wqs = W2s + 128 * 128;
    u16* Wks = Wqs + 128 * 128;
    u16* Wvs = Wks + 128 * 128;

    const int* esrc = eidx;
    const int* etgt = eidx + E_;

    hipMemsetAsync(hist, 0, N_ * sizeof(int), stream);

    setup_kernel<<<64 + (E_ + 255) / 256, 256, 0, stream>>>(
        W1, W2, Wq, Wk, Wv, W1s, W2s, Wqs, Wks, Wvs,
        edge_emb, bk, bv, We, be, Kt, Vt, ebt, etgt, hist);
    scan_kernel<<<1, 1024, 0, stream>>>(hist, offs, cursor);
    scatter_qkv_kernel<<<625 + 313, 256, 0, stream>>>(
        esrc, etgt, etype, cursor, sorted,
        hidden, time_emb, Wqs, Wks, Wvs, bq, Kt, ebt, Qb, Kb, Vb, biasT);
    attn_kernel<<<(B_ * N_) / 4, 256, 0, stream>>>(Qb, Kb, Vb, Vt, biasT, offs, sorted, aggb);
    mlp_mfma_kernel<<<313, 256, 0, stream>>>(hidden, aggb, time_emb, W1s, W2s, b1, b2, gamma, beta, out);
}

// Round 9
// 196.044 us; speedup vs baseline: 1.0044x; 1.0044x over previous
//
#include <hip/hip_runtime.h>
#include <math.h>

constexpr int B_  = 2;
constexpr int N_  = 10000;
constexpr int E_  = 160000;
constexpr int H_  = 128;
constexpr int ET_ = 8;
constexpr float EPS_ = 1e-5f;
constexpr float RSQH = 0.08838834764831845f; // 1/sqrt(128)

typedef __bf16 bf16x8 __attribute__((ext_vector_type(8)));
typedef short  short8 __attribute__((ext_vector_type(8)));
typedef float  f32x4  __attribute__((ext_vector_type(4)));
typedef unsigned short u16;

__device__ inline u16 bf16b(float f) {
    return __builtin_bit_cast(u16, (__bf16)f);
}

__device__ inline bf16x8 ldfrag(const u16* __restrict__ W, int kc, int nt, int lane) {
    short8 s = *(const short8*)(W + ((kc * 8 + nt) * 64 + lane) * 8);
    return __builtin_bit_cast(bf16x8, s);
}

// ---------------------------------------------------------------------------
// Fused setup: blocks [0,56) weight-prep, [56,64) edge-type tables,
// [64,689) tgt histogram.
// ---------------------------------------------------------------------------
__global__ __launch_bounds__(256)
void setup_kernel(const float* __restrict__ W1, const float* __restrict__ W2,
                  const float* __restrict__ Wq, const float* __restrict__ Wk,
                  const float* __restrict__ Wv,
                  u16* __restrict__ W1s, u16* __restrict__ W2s,
                  u16* __restrict__ Wqs, u16* __restrict__ Wks, u16* __restrict__ Wvs,
                  const float* __restrict__ edge_emb,
                  const float* __restrict__ bk, const float* __restrict__ bv,
                  const float* __restrict__ We, const float* __restrict__ be,
                  float* __restrict__ Kt, float* __restrict__ Vt, float* __restrict__ eb,
                  const int* __restrict__ tgt, int* __restrict__ hist)
{
    const int bid = blockIdx.x, tid = threadIdx.x;
    if (bid < 56) {
        // weight prep: f32 [Kx128] -> bf16 B-frag swizzle
        int unit = bid >> 1, half = bid & 1;
        const float* src; u16* dst; int kc;
        if (unit < 12)      { src = W1; dst = W1s; kc = unit; }
        else if (unit < 16) { src = W2; dst = W2s; kc = unit - 12; }
        else if (unit < 20) { src = Wq; dst = Wqs; kc = unit - 16; }
        else if (unit < 24) { src = Wk; dst = Wks; kc = unit - 20; }
        else                { src = Wv; dst = Wvs; kc = unit - 24; }
        int nt = half * 4 + (tid >> 6), lane = tid & 63;
        int q = lane >> 4, c = lane & 15;
        int kbase = kc * 32 + q * 8;
        int col = nt * 16 + c;
        u16* out = dst + ((kc * 8 + nt) * 64 + lane) * 8;
#pragma unroll
        for (int j = 0; j < 8; ++j)
            out[j] = bf16b(src[(kbase + j) * H_ + col]);
    } else if (bid < 64) {
        // edge-type tables: Kt=e@Wk+bk, Vt=e@Wv+bv, eb=e@We+be
        int t = bid - 56;
        const float* ep = edge_emb + t * H_;
        __shared__ float red[2];
        int j = tid;
        if (j < 128) {
            float ak = bk[j], av = bv[j];
            for (int d = 0; d < H_; d += 4) {
                float e0 = ep[d], e1 = ep[d+1], e2 = ep[d+2], e3 = ep[d+3];
                ak += e0*Wk[(d+0)*H_+j] + e1*Wk[(d+1)*H_+j] + e2*Wk[(d+2)*H_+j] + e3*Wk[(d+3)*H_+j];
                av += e0*Wv[(d+0)*H_+j] + e1*Wv[(d+1)*H_+j] + e2*Wv[(d+2)*H_+j] + e3*Wv[(d+3)*H_+j];
            }
            Kt[t*H_ + j] = ak;
            Vt[t*H_ + j] = av;
            float pe = ep[j] * We[j];
#pragma unroll
            for (int off = 32; off; off >>= 1) pe += __shfl_xor(pe, off);
            if ((j & 63) == 0) red[j >> 6] = pe;
        }
        __syncthreads();
        if (j == 0) eb[t] = red[0] + red[1] + be[0];
    } else {
        int e = (bid - 64) * 256 + tid;
        if (e < E_) atomicAdd(&hist[tgt[e]], 1);
    }
}

// ---------------------------------------------------------------------------
// Single-pass exclusive scan: 1024 threads x 10 elements, 2 barriers.
// ---------------------------------------------------------------------------
__global__ __launch_bounds__(1024)
void scan_kernel(const int* __restrict__ hist, int* __restrict__ offs,
                 int* __restrict__ cursor)
{
    __shared__ int winc[16];
    const int tid = threadIdx.x, wave = tid >> 6, lane = tid & 63;
    int v[10];
    const int idx0 = tid * 10;
    int tot = 0;
#pragma unroll
    for (int i = 0; i < 10; ++i) {
        int idx = idx0 + i;
        v[i] = (idx < N_) ? hist[idx] : 0;
        tot += v[i];
    }
    int s = tot;
#pragma unroll
    for (int off = 1; off < 64; off <<= 1) {
        int t = __shfl_up(s, off);
        if (lane >= off) s += t;
    }
    if (lane == 63) winc[wave] = s;
    __syncthreads();
    if (tid < 16) {
        int si = winc[tid];
#pragma unroll
        for (int off = 1; off < 16; off <<= 1) {
            int t = __shfl_up(si, off);
            if (tid >= off) si += t;
        }
        winc[tid] = si;   // inclusive scan of wave totals
    }
    __syncthreads();
    int wbase = (wave == 0) ? 0 : winc[wave - 1];
    int run = wbase + (s - tot);
#pragma unroll
    for (int i = 0; i < 10; ++i) {
        int idx = idx0 + i;
        if (idx < N_) { offs[idx] = run; cursor[idx] = run; }
        run += v[i];
    }
    if (tid == 0) offs[N_] = winc[15];
}

// ---------------------------------------------------------------------------
// Fused scatter (blocks [0,625)) + Q/K/V MFMA (blocks [625,938)).
// ---------------------------------------------------------------------------
__global__ __launch_bounds__(256)
void scatter_qkv_kernel(const int* __restrict__ src, const int* __restrict__ tgt,
                        const int* __restrict__ type, int* __restrict__ cursor,
                        int* __restrict__ sorted,
                        const float* __restrict__ hidden, const float* __restrict__ time_emb,
                        const u16* __restrict__ Wqs, const u16* __restrict__ Wks,
                        const u16* __restrict__ Wvs, const float* __restrict__ bq,
                        u16* __restrict__ Q, u16* __restrict__ K, u16* __restrict__ V)
{
    if (blockIdx.x < 625) {
        int e = blockIdx.x * 256 + threadIdx.x;
        if (e < E_) {
            int t = tgt[e];
            int pos = atomicAdd(&cursor[t], 1);
            sorted[pos] = src[e] | (type[e] << 16);
        }
        return;
    }
    const int wv = threadIdx.x >> 6, lane = threadIdx.x & 63;
    const int tile = (blockIdx.x - 625) * 4 + wv;
    if (tile >= (B_ * N_) / 16) return;
    const int nbase = tile * 16;
    const int m = lane & 15, q = lane >> 4;
    const int koff = q * 8;

    bf16x8 aq[4], av[4];
    const float* hp = hidden   + (nbase + m) * H_ + koff;
    const float* tp = time_emb + (nbase + m) * H_ + koff;
#pragma unroll
    for (int kc = 0; kc < 4; ++kc) {
        float4 h0 = *(const float4*)(hp + kc * 32);
        float4 h1 = *(const float4*)(hp + kc * 32 + 4);
        float4 t0 = *(const float4*)(tp + kc * 32);
        float4 t1 = *(const float4*)(tp + kc * 32 + 4);
        bf16x8 fv, fq;
        fv[0]=(__bf16)h0.x; fv[1]=(__bf16)h0.y; fv[2]=(__bf16)h0.z; fv[3]=(__bf16)h0.w;
        fv[4]=(__bf16)h1.x; fv[5]=(__bf16)h1.y; fv[6]=(__bf16)h1.z; fv[7]=(__bf16)h1.w;
        fq[0]=(__bf16)(h0.x+t0.x); fq[1]=(__bf16)(h0.y+t0.y);
        fq[2]=(__bf16)(h0.z+t0.z); fq[3]=(__bf16)(h0.w+t0.w);
        fq[4]=(__bf16)(h1.x+t1.x); fq[5]=(__bf16)(h1.y+t1.y);
        fq[6]=(__bf16)(h1.z+t1.z); fq[7]=(__bf16)(h1.w+t1.w);
        av[kc] = fv; aq[kc] = fq;
    }

    f32x4 accq[8], acck[8], accv[8];
#pragma unroll
    for (int nt = 0; nt < 8; ++nt) { accq[nt] = (f32x4)0.f; acck[nt] = (f32x4)0.f; accv[nt] = (f32x4)0.f; }

#pragma unroll
    for (int kc = 0; kc < 4; ++kc) {
#pragma unroll
        for (int nt = 0; nt < 8; ++nt) {
            bf16x8 bfq = ldfrag(Wqs, kc, nt, lane);
            bf16x8 bfk = ldfrag(Wks, kc, nt, lane);
            bf16x8 bfv = ldfrag(Wvs, kc, nt, lane);
            accq[nt] = __builtin_amdgcn_mfma_f32_16x16x32_bf16(aq[kc], bfq, accq[nt], 0, 0, 0);
            acck[nt] = __builtin_amdgcn_mfma_f32_16x16x32_bf16(aq[kc], bfk, acck[nt], 0, 0, 0);
            accv[nt] = __builtin_amdgcn_mfma_f32_16x16x32_bf16(av[kc], bfv, accv[nt], 0, 0, 0);
        }
    }

#pragma unroll
    for (int nt = 0; nt < 8; ++nt) {
        int col = nt * 16 + m;
        float bqc = bq[col];
#pragma unroll
        for (int r = 0; r < 4; ++r) {
            int node = nbase + q * 4 + r;
            Q[node * H_ + col] = bf16b(accq[nt][r] + bqc);
            K[node * H_ + col] = bf16b(acck[nt][r]);
            V[node * H_ + col] = bf16b(accv[nt][r]);
        }
    }
}

// ---------------------------------------------------------------------------
// Attention: one wave per (b,node); 16-lane groups own edges, 2 in flight.
// Two-pass per 64-edge chunk; packed edge words staged in LDS pre-divergence.
// ---------------------------------------------------------------------------
__global__ __launch_bounds__(256)
void attn_kernel(const u16* __restrict__ Qb, const u16* __restrict__ Kb,
                 const u16* __restrict__ Vb,
                 const float* __restrict__ Kt, const float* __restrict__ Vt,
                 const float* __restrict__ eb,
                 const int* __restrict__ offs, const int* __restrict__ sorted,
                 u16* __restrict__ aggb)
{
    __shared__ float logit_s[4][64];
    __shared__ float bias_s[4][8];
    __shared__ int   pk_s[4][64];
    __shared__ __align__(16) u16 vt_s[8][128];

    const int tid = threadIdx.x;
    const int wv = tid >> 6, lane = tid & 63;
    const int g = lane >> 4, lam = lane & 15;

    for (int idx = tid; idx < ET_ * H_; idx += 256)
        vt_s[idx >> 7][idx & 127] = bf16b(Vt[idx]);
    __syncthreads();

    const int b = blockIdx.x & 1;                 // batch-parity XCD swizzle
    const int n = (blockIdx.x >> 1) * 4 + wv;
    const int bn = b * N_ + n;
    const int beg = offs[n], end = offs[n + 1];
    const int bbase = b * N_;

    float q[8];
    {
        short8 s8 = *(const short8*)(Qb + (size_t)bn * H_ + lam * 8);
        bf16x8 qa = __builtin_bit_cast(bf16x8, s8);
#pragma unroll
        for (int j = 0; j < 8; ++j) q[j] = (float)qa[j];
    }

    {   // per-type logit bias: group g computes types 2g, 2g+1
        const float* k0p = Kt + (2 * g) * H_ + lam * 8;
        const float* k1p = Kt + (2 * g + 1) * H_ + lam * 8;
        float p0 = 0.f, p1 = 0.f;
#pragma unroll
        for (int j = 0; j < 8; ++j) { p0 += q[j] * k0p[j]; p1 += q[j] * k1p[j]; }
#pragma unroll
        for (int msk = 1; msk < 16; msk <<= 1) {
            p0 += __shfl_xor(p0, msk);
            p1 += __shfl_xor(p1, msk);
        }
        if (lam == 0) {
            bias_s[wv][2 * g]     = p0 * RSQH + eb[2 * g];
            bias_s[wv][2 * g + 1] = p1 * RSQH + eb[2 * g + 1];
        }
    }

    float m_run = -INFINITY, l = 0.f;
    float acc[8];
#pragma unroll
    for (int j = 0; j < 8; ++j) acc[j] = 0.f;

    for (int cb = beg; cb < end; cb += 64) {
        const int cnt = min(64, end - cb);
        pk_s[wv][lane] = (cb + lane < end) ? sorted[cb + lane] : 0;  // pre-divergence

        // ---- pass 1: logits + chunk max (2 edges in flight per group) ----
        float gmax = -INFINITY;
        int c = g;
        for (; c + 4 < cnt; c += 8) {
            int pk0 = pk_s[wv][c];
            int pk1 = pk_s[wv][c + 4];
            int s0 = pk0 & 0xFFFF, t0 = pk0 >> 16;
            int s1 = pk1 & 0xFFFF, t1 = pk1 >> 16;
            short8 k80 = *(const short8*)(Kb + (size_t)(bbase + s0) * H_ + lam * 8);
            short8 k81 = *(const short8*)(Kb + (size_t)(bbase + s1) * H_ + lam * 8);
            bf16x8 ka0 = __builtin_bit_cast(bf16x8, k80);
            bf16x8 ka1 = __builtin_bit_cast(bf16x8, k81);
            float p0 = 0.f, p1 = 0.f;
#pragma unroll
            for (int j = 0; j < 8; ++j) {
                p0 += q[j] * (float)ka0[j];
                p1 += q[j] * (float)ka1[j];
            }
#pragma unroll
            for (int msk = 1; msk < 16; msk <<= 1) {
                p0 += __shfl_xor(p0, msk);
                p1 += __shfl_xor(p1, msk);
            }
            float lg0 = p0 * RSQH + bias_s[wv][t0];
            float lg1 = p1 * RSQH + bias_s[wv][t1];
            if (lam == 0) { logit_s[wv][c] = lg0; logit_s[wv][c + 4] = lg1; }
            gmax = fmaxf(gmax, fmaxf(lg0, lg1));
        }
        if (c < cnt) {
            int pk0 = pk_s[wv][c];
            int s0 = pk0 & 0xFFFF, t0 = pk0 >> 16;
            short8 k80 = *(const short8*)(Kb + (size_t)(bbase + s0) * H_ + lam * 8);
            bf16x8 ka0 = __builtin_bit_cast(bf16x8, k80);
            float p0 = 0.f;
#pragma unroll
            for (int j = 0; j < 8; ++j) p0 += q[j] * (float)ka0[j];
#pragma unroll
            for (int msk = 1; msk < 16; msk <<= 1) p0 += __shfl_xor(p0, msk);
            float lg0 = p0 * RSQH + bias_s[wv][t0];
            if (lam == 0) logit_s[wv][c] = lg0;
            gmax = fmaxf(gmax, lg0);
        }
        gmax = fmaxf(gmax, __shfl_xor(gmax, 16));
        gmax = fmaxf(gmax, __shfl_xor(gmax, 32));
        float Mn = fmaxf(m_run, gmax);
        float rs = __expf(m_run - Mn);   // first chunk: exp(-inf)=0
        l *= rs;
#pragma unroll
        for (int j = 0; j < 8; ++j) acc[j] *= rs;
        m_run = Mn;

        // ---- pass 2: weights + V accumulate (2 edges in flight) ----
        c = g;
        for (; c + 4 < cnt; c += 8) {
            int pk0 = pk_s[wv][c];
            int pk1 = pk_s[wv][c + 4];
            int s0 = pk0 & 0xFFFF, t0 = pk0 >> 16;
            int s1 = pk1 & 0xFFFF, t1 = pk1 >> 16;
            short8 v80  = *(const short8*)(Vb + (size_t)(bbase + s0) * H_ + lam * 8);
            short8 v81  = *(const short8*)(Vb + (size_t)(bbase + s1) * H_ + lam * 8);
            short8 vt80 = *(const short8*)(&vt_s[t0][lam * 8]);
            short8 vt81 = *(const short8*)(&vt_s[t1][lam * 8]);
            float w0 = __expf(logit_s[wv][c] - Mn);
            float w1 = __expf(logit_s[wv][c + 4] - Mn);
            l += w0 + w1;
            bf16x8 va0  = __builtin_bit_cast(bf16x8, v80);
            bf16x8 va1  = __builtin_bit_cast(bf16x8, v81);
            bf16x8 vta0 = __builtin_bit_cast(bf16x8, vt80);
            bf16x8 vta1 = __builtin_bit_cast(bf16x8, vt81);
#pragma unroll
            for (int j = 0; j < 8; ++j)
                acc[j] += w0 * ((float)va0[j] + (float)vta0[j])
                        + w1 * ((float)va1[j] + (float)vta1[j]);
        }
        if (c < cnt) {
            int pk0 = pk_s[wv][c];
            int s0 = pk0 & 0xFFFF, t0 = pk0 >> 16;
            short8 v80  = *(const short8*)(Vb + (size_t)(bbase + s0) * H_ + lam * 8);
            short8 vt80 = *(const short8*)(&vt_s[t0][lam * 8]);
            float w0 = __expf(logit_s[wv][c] - Mn);
            l += w0;
            bf16x8 va0  = __builtin_bit_cast(bf16x8, v80);
            bf16x8 vta0 = __builtin_bit_cast(bf16x8, vt80);
#pragma unroll
            for (int j = 0; j < 8; ++j)
                acc[j] += w0 * ((float)va0[j] + (float)vta0[j]);
        }
    }

    // merge the 4 groups (reconverged here)
#pragma unroll
    for (int j = 0; j < 8; ++j) {
        acc[j] += __shfl_xor(acc[j], 16);
        acc[j] += __shfl_xor(acc[j], 32);
    }
    l += __shfl_xor(l, 16);
    l += __shfl_xor(l, 32);

    if (g == 0) {
        float invL = (end > beg) ? 1.f / l : 0.f;
        bf16x8 o;
#pragma unroll
        for (int j = 0; j < 8; ++j) o[j] = (__bf16)(acc[j] * invL);
        *(short8*)(aggb + (size_t)bn * H_ + lam * 8) = __builtin_bit_cast(short8, o);
    }
}

// ---------------------------------------------------------------------------
// MLP + residual + LayerNorm via MFMA.
// ---------------------------------------------------------------------------
__global__ __launch_bounds__(256)
void mlp_mfma_kernel(const float* __restrict__ hidden, const u16* __restrict__ aggb,
                     const float* __restrict__ time_emb,
                     const u16* __restrict__ W1s, const u16* __restrict__ W2s,
                     const float* __restrict__ b1, const float* __restrict__ b2,
                     const float* __restrict__ gamma, const float* __restrict__ beta,
                     float* __restrict__ out)
{
    __shared__ __align__(16) u16 h1s[4][16][136];
    const int wv = threadIdx.x >> 6, lane = threadIdx.x & 63;
    const int tile = blockIdx.x * 4 + wv;
    if (tile >= (B_ * N_) / 16) return;
    const int nbase = tile * 16;
    const int m = lane & 15, q = lane >> 4;
    const int koff = q * 8;

    bf16x8 a[12];
    const float* hp = hidden   + (nbase + m) * H_ + koff;
    const float* tp = time_emb + (nbase + m) * H_ + koff;
    const u16*   ap = aggb + (size_t)(nbase + m) * H_ + koff;
#pragma unroll
    for (int kc = 0; kc < 4; ++kc) {
        float4 h0 = *(const float4*)(hp + kc * 32);
        float4 h1 = *(const float4*)(hp + kc * 32 + 4);
        float4 t0 = *(const float4*)(tp + kc * 32);
        float4 t1 = *(const float4*)(tp + kc * 32 + 4);
        bf16x8 fh, ft;
        fh[0]=(__bf16)h0.x; fh[1]=(__bf16)h0.y; fh[2]=(__bf16)h0.z; fh[3]=(__bf16)h0.w;
        fh[4]=(__bf16)h1.x; fh[5]=(__bf16)h1.y; fh[6]=(__bf16)h1.z; fh[7]=(__bf16)h1.w;
        ft[0]=(__bf16)t0.x; ft[1]=(__bf16)t0.y; ft[2]=(__bf16)t0.z; ft[3]=(__bf16)t0.w;
        ft[4]=(__bf16)t1.x; ft[5]=(__bf16)t1.y; ft[6]=(__bf16)t1.z; ft[7]=(__bf16)t1.w;
        a[0 * 4 + kc] = fh;
        a[2 * 4 + kc] = ft;
        short8 s8 = *(const short8*)(ap + kc * 32);
        a[1 * 4 + kc] = __builtin_bit_cast(bf16x8, s8);
    }

    f32x4 acc[8];
#pragma unroll
    for (int nt = 0; nt < 8; ++nt) acc[nt] = (f32x4)0.f;
#pragma unroll
    for (int kc = 0; kc < 12; ++kc) {
#pragma unroll
        for (int nt = 0; nt < 8; ++nt) {
            bf16x8 bf = ldfrag(W1s, kc, nt, lane);
            acc[nt] = __builtin_amdgcn_mfma_f32_16x16x32_bf16(a[kc], bf, acc[nt], 0, 0, 0);
        }
    }

#pragma unroll
    for (int nt = 0; nt < 8; ++nt) {
        int col = nt * 16 + m;
        float bb = b1[col];
#pragma unroll
        for (int r = 0; r < 4; ++r) {
            float v = acc[nt][r] + bb;
            float h = v / (1.f + __expf(-v));
            h1s[wv][q * 4 + r][col] = bf16b(h);
        }
    }

    f32x4 acc2[8];
#pragma unroll
    for (int nt = 0; nt < 8; ++nt) acc2[nt] = (f32x4)0.f;
#pragma unroll
    for (int kc = 0; kc < 4; ++kc) {
        short8 s8 = *(const short8*)&h1s[wv][m][kc * 32 + koff];
        bf16x8 a2 = __builtin_bit_cast(bf16x8, s8);
#pragma unroll
        for (int nt = 0; nt < 8; ++nt) {
            bf16x8 bf = ldfrag(W2s, kc, nt, lane);
            acc2[nt] = __builtin_amdgcn_mfma_f32_16x16x32_bf16(a2, bf, acc2[nt], 0, 0, 0);
        }
    }

    float x[8][4];
#pragma unroll
    for (int nt = 0; nt < 8; ++nt) {
        int col = nt * 16 + m;
        float bb = b2[col];
#pragma unroll
        for (int r = 0; r < 4; ++r) {
            int node = nbase + q * 4 + r;
            x[nt][r] = hidden[node * H_ + col] + acc2[nt][r] + bb;
        }
    }
#pragma unroll
    for (int r = 0; r < 4; ++r) {
        float s = 0.f, ss = 0.f;
#pragma unroll
        for (int nt = 0; nt < 8; ++nt) { s += x[nt][r]; ss += x[nt][r] * x[nt][r]; }
#pragma unroll
        for (int off = 1; off < 16; off <<= 1) {
            s  += __shfl_xor(s, off);
            ss += __shfl_xor(ss, off);
        }
        float mu  = s * (1.f / H_);
        float var = ss * (1.f / H_) - mu * mu;
        float rs  = rsqrtf(var + EPS_);
        int node = nbase + q * 4 + r;
#pragma unroll
        for (int nt = 0; nt < 8; ++nt) {
            int col = nt * 16 + m;
            out[node * H_ + col] = (x[nt][r] - mu) * rs * gamma[col] + beta[col];
        }
    }
}

// ---------------------------------------------------------------------------
extern "C" void kernel_launch(void* const* d_in, const int* in_sizes, int n_in,
                              void* d_out, int out_size, void* d_ws, size_t ws_size,
                              hipStream_t stream)
{
    const float* hidden   = (const float*)d_in[0];
    const float* time_emb = (const float*)d_in[1];
    const int*   eidx     = (const int*)d_in[2];
    const int*   etype    = (const int*)d_in[3];
    const float* edge_emb = (const float*)d_in[4];
    const float* Wq = (const float*)d_in[5];
    const float* bq = (const float*)d_in[6];
    const float* Wk = (const float*)d_in[7];
    const float* bk = (const float*)d_in[8];
    const float* Wv = (const float*)d_in[9];
    const float* bv = (const float*)d_in[10];
    const float* We = (const float*)d_in[11];
    const float* be = (const float*)d_in[12];
    const float* W1 = (const float*)d_in[13];
    const float* b1 = (const float*)d_in[14];
    const float* W2 = (const float*)d_in[15];
    const float* b2 = (const float*)d_in[16];
    const float* gamma = (const float*)d_in[17];
    const float* beta  = (const float*)d_in[18];
    float* out = (float*)d_out;

    constexpr int BNH = B_ * N_ * H_;
    u16* Qb   = (u16*)d_ws;
    u16* Kb   = Qb + BNH;
    u16* Vb   = Kb + BNH;
    u16* aggb = Vb + BNH;
    float* Kt  = (float*)(aggb + BNH);
    float* Vt  = Kt + ET_ * H_;
    float* ebt = Vt + ET_ * H_;
    int* hist   = (int*)(ebt + ET_);
    int* offs   = hist + N_;
    int* cursor = offs + (N_ + 1);
    int* sorted = cursor + N_;
    uintptr_t wp = (uintptr_t)(sorted + E_);
    wp = (wp + 15) & ~(uintptr_t)15;
    u16* W1s = (u16*)wp;
    u16* W2s = W1s + 384 * 128;
    u16* Wqs = W2s + 128 * 128;
    u16* Wks = Wqs + 128 * 128;
    u16* Wvs = Wks + 128 * 128;

    const int* esrc = eidx;
    const int* etgt = eidx + E_;

    hipMemsetAsync(hist, 0, N_ * sizeof(int), stream);

    setup_kernel<<<64 + (E_ + 255) / 256, 256, 0, stream>>>(
        W1, W2, Wq, Wk, Wv, W1s, W2s, Wqs, Wks, Wvs,
        edge_emb, bk, bv, We, be, Kt, Vt, ebt, etgt, hist);
    scan_kernel<<<1, 1024, 0, stream>>>(hist, offs, cursor);
    scatter_qkv_kernel<<<625 + 313, 256, 0, stream>>>(
        esrc, etgt, etype, cursor, sorted,
        hidden, time_emb, Wqs, Wks, Wvs, bq, Qb, Kb, Vb);
    attn_kernel<<<(B_ * N_) / 4, 256, 0, stream>>>(Qb, Kb, Vb, Kt, Vt, ebt, offs, sorted, aggb);
    mlp_mfma_kernel<<<313, 256, 0, stream>>>(hidden, aggb, time_emb, W1s, W2s, b1, b2, gamma, beta, out);
}